// Round 6
// baseline (188.692 us; speedup 1.0000x reference)
//
#include <hip/hip_runtime.h>

#define T_SEQ 50
#define BATCH 8192
#define INPUT 33
#define HID   256
#define BTILE 16
#define NTH   512

typedef __attribute__((ext_vector_type(8))) short short8;
typedef __attribute__((ext_vector_type(4))) float float4v;

// LDS: h double-buffer ONLY (x never staged; W' in regs). 16.9 KB/block ->
// 2 blocks/CU co-resident (the lever this round: independent barriers).
#define H_STRIDE 264                        // 256 + 8 pad
#define HBUF (BTILE * H_STRIDE)             // 4224 shorts
#define LDS_SHORTS (2 * HBUF)               // 8448 shorts = 16896 B

__device__ __forceinline__ short f2bf(float v) {   // RNE f32 -> bf16 bits
  unsigned u = __builtin_bit_cast(unsigned, v);
  u = (u + 0x7FFFu + ((u >> 16) & 1u)) >> 16;
  return (short)u;
}

// One step. h read from lds[HR], next-h written to lds[HW]. x fragments come
// straight from global (L2/L3-resident; per-wave 2KB). One barrier per step;
// no vmcnt drain (stores retire behind the next step's x-load wait).
#define CSTEP(HR, HW, T)                                                      \
  {                                                                           \
    const float* xt = xrow + (size_t)(T) * xstep;                             \
    float4v xr0 = *(const float4v*)xt;                                        \
    float4v xr1 = *(const float4v*)(xt + 4);                                  \
    const float* xt32 = xcol32 + (size_t)(T) * xstep;                         \
    float x32_0 = xt32[0], x32_1 = xt32[33], x32_2 = xt32[66], x32_3 = xt32[99]; \
    float4v acc[2];                                                           \
    _Pragma("unroll") for (int n = 0; n < 2; ++n)                             \
      _Pragma("unroll") for (int i = 0; i < 4; ++i)                           \
        acc[n][i] = hst[n][i] + bc[n];                                        \
    const short* hb = lds + (HR);                                             \
    _Pragma("unroll") for (int ks = 0; ks < 8; ++ks) {                        \
      short8 a0 = *(const short8*)(hb + colA * H_STRIDE + ks * 32 + kq * 8);  \
      acc[0] = __builtin_amdgcn_mfma_f32_16x16x32_bf16(a0, wf[0][ks], acc[0], 0, 0, 0); \
      acc[1] = __builtin_amdgcn_mfma_f32_16x16x32_bf16(a0, wf[1][ks], acc[1], 0, 0, 0); \
    }                                                                         \
    short8 xa;                                                                \
    xa[0] = f2bf(xr0[0]); xa[1] = f2bf(xr0[1]);                               \
    xa[2] = f2bf(xr0[2]); xa[3] = f2bf(xr0[3]);                               \
    xa[4] = f2bf(xr1[0]); xa[5] = f2bf(xr1[1]);                               \
    xa[6] = f2bf(xr1[2]); xa[7] = f2bf(xr1[3]);                               \
    acc[0] = __builtin_amdgcn_mfma_f32_16x16x32_bf16(xa, win0[0], acc[0], 0, 0, 0); \
    acc[1] = __builtin_amdgcn_mfma_f32_16x16x32_bf16(xa, win0[1], acc[1], 0, 0, 0); \
    _Pragma("unroll") for (int n = 0; n < 2; ++n) {                           \
      acc[n][0] += w32[n] * x32_0;                                            \
      acc[n][1] += w32[n] * x32_1;                                            \
      acc[n][2] += w32[n] * x32_2;                                            \
      acc[n][3] += w32[n] * x32_3;                                            \
    }                                                                         \
    _Pragma("unroll") for (int n = 0; n < 2; ++n)                             \
      _Pragma("unroll") for (int i = 0; i < 4; ++i) {                         \
        float hn = fmaxf(0.5f * acc[n][i], 0.0f);                             \
        hst[n][i] = hn;                                                       \
        outp[i * HID + n * 16] = hn;                                          \
      }                                                                       \
    _Pragma("unroll") for (int n = 0; n < 2; ++n)                             \
      _Pragma("unroll") for (int i = 0; i < 4; ++i)                           \
        lds[(HW) + (kq * 4 + i) * H_STRIDE + c0 + n * 16 + colA] =            \
            f2bf(hst[n][i]);                                                  \
    __builtin_amdgcn_sched_barrier(0);                                        \
    asm volatile("s_waitcnt lgkmcnt(0)" ::: "memory");                        \
    __builtin_amdgcn_s_barrier();                                             \
    __builtin_amdgcn_sched_barrier(0);                                        \
    outp += outstep;                                                          \
  }

__global__ __launch_bounds__(NTH, 4)
void ctrnn_kernel(const float* __restrict__ x, const int* __restrict__ sub_id,
                  const float* __restrict__ gates, const float* __restrict__ W_in,
                  const float* __restrict__ b_in, const float* __restrict__ W_h,
                  const float* __restrict__ b_h, float* __restrict__ out)
{
  __shared__ short lds[LDS_SHORTS];
  const int tid  = threadIdx.x;
  const int lane = tid & 63;
  const int wave = tid >> 6;
  const int colA = lane & 15;   // A-row / C-col within tile
  const int kq   = lane >> 4;   // k-chunk / C-row group
  const int c0   = wave * 32;   // wave's output-column base (8 waves x 32)
  const int brow0 = blockIdx.x * BTILE;

  const int sid = sub_id[0];
  const float* grow = gates + sid * HID;

  // ---- zero h buffer 0 (h0 = 0) ----
  {
    int* ldsi = (int*)lds;
    for (int i = tid; i < HBUF / 2; i += NTH) ldsi[i] = 0;
  }

  // ---- t-invariant operands in registers ----
  short8 wf[2][8];    // W_h' = diag(g)*W_h B-fragments (64 VGPRs)
  short8 win0[2];     // W_in k=0..31 B-fragments (8 VGPRs)
  float  w32[2];      // W_in k=32 column (rank-1 term, f32)
  float  bc[2];       // b_in + g*b_h
  #pragma unroll
  for (int n = 0; n < 2; ++n) {
    const int col = c0 + n * 16 + colA;
    const float g = grow[col];
    #pragma unroll
    for (int ks = 0; ks < 8; ++ks) {
      const float* wp = W_h + col * HID + ks * 32 + kq * 8;
      float4v w0 = *(const float4v*)wp;
      float4v w1 = *(const float4v*)(wp + 4);
      short8 f;
      f[0] = f2bf(g * w0[0]); f[1] = f2bf(g * w0[1]);
      f[2] = f2bf(g * w0[2]); f[3] = f2bf(g * w0[3]);
      f[4] = f2bf(g * w1[0]); f[5] = f2bf(g * w1[1]);
      f[6] = f2bf(g * w1[2]); f[7] = f2bf(g * w1[3]);
      wf[n][ks] = f;
    }
    {
      const float* wip = W_in + col * INPUT + kq * 8;   // k = kq*8..kq*8+7 < 32
      short8 f;
      #pragma unroll
      for (int j = 0; j < 8; ++j) f[j] = f2bf(wip[j]);
      win0[n] = f;
    }
    w32[n] = W_in[col * INPUT + 32];
    bc[n]  = b_in[col] + g * b_h[col];
  }

  // x addressing: A-fragment row = colA, k = kq*8..kq*8+7 (all < 32 valid);
  // rank-1 rows = kq*4..kq*4+3 at k=32.
  const float* xrow   = x + (size_t)(brow0 + colA) * INPUT + kq * 8;
  const float* xcol32 = x + (size_t)(brow0 + kq * 4) * INPUT + 32;
  const int xstep = BATCH * INPUT;

  // persistent f32 h master at MFMA C-layout: col = c0+n*16+colA, row = kq*4+i
  float4v hst[2];
  #pragma unroll
  for (int n = 0; n < 2; ++n)
    #pragma unroll
    for (int i = 0; i < 4; ++i) hst[n][i] = 0.0f;

  float* outp = out + (size_t)(brow0 + kq * 4) * HID + c0 + colA;
  const int outstep = BATCH * HID;

  __syncthreads();   // h0 zero-fill visible to all waves

  #pragma unroll 1
  for (int t2 = 0; t2 < T_SEQ / 2; ++t2) {
    CSTEP(0, HBUF, 2 * t2);        // even: read buf0, write buf1
    CSTEP(HBUF, 0, 2 * t2 + 1);    // odd:  read buf1, write buf0
  }

  // h_last = h after step T-1 (still in registers)
  {
    float* hp = out + (size_t)T_SEQ * BATCH * HID +
                (size_t)(brow0 + kq * 4) * HID + c0 + colA;
    #pragma unroll
    for (int n = 0; n < 2; ++n)
      #pragma unroll
      for (int i = 0; i < 4; ++i)
        hp[i * HID + n * 16] = hst[n][i];
  }
}

extern "C" void kernel_launch(void* const* d_in, const int* in_sizes, int n_in,
                              void* d_out, int out_size, void* d_ws, size_t ws_size,
                              hipStream_t stream) {
  const float* x    = (const float*)d_in[0];
  const int*   sid  = (const int*)  d_in[1];
  const float* gts  = (const float*)d_in[2];
  const float* W_in = (const float*)d_in[3];
  const float* b_in = (const float*)d_in[4];
  const float* W_h  = (const float*)d_in[5];
  const float* b_h  = (const float*)d_in[6];
  float* out = (float*)d_out;

  ctrnn_kernel<<<BATCH / BTILE, NTH, 0, stream>>>(x, sid, gts, W_in, b_in, W_h, b_h, out);
}

// Round 7
// 138.579 us; speedup vs baseline: 1.3616x; 1.3616x over previous
//
#include <hip/hip_runtime.h>

#define T_SEQ 50
#define BATCH 8192
#define INPUT 33
#define HID   256
#define BTILE 32
#define NTH   512

typedef __attribute__((ext_vector_type(8))) short short8;
typedef __attribute__((ext_vector_type(4))) short short4v;
typedef __attribute__((ext_vector_type(4))) float float4v;

// ---- LDS layout (units: shorts unless noted) ----
// h double-buffer: bf16, stride 264 (16B-aligned rows, b128-friendly)
#define H_STRIDE 264
#define HBUF (BTILE * H_STRIDE)            // 8448
#define H0 0
#define H1 HBUF
// ALL 50 x-tiles staged upfront: bf16, stride 36 (cols 0..32 used).
// Read via 2x ds_read_b64 (8B-aligned; stride 36*2=72B). 115200 B.
#define XA_OFF (2 * HBUF)                  // 16896
#define XA_T   (BTILE * 36)                // 1152 shorts per timestep
// k=32 column as f32 plane [T][BTILE]: byte offset 148992, 6400 B.
#define X32_BYTE ((XA_OFF + T_SEQ * XA_T) * 2)
#define LDS_BYTES (X32_BYTE + T_SEQ * BTILE * 4)   // 155392 <= 163840

__device__ __forceinline__ short f2bf(float v) {   // RNE f32 -> bf16 bits
  unsigned u = __builtin_bit_cast(unsigned, v);
  u = (u + 0x7FFFu + ((u >> 16) & 1u)) >> 16;
  return (short)u;
}
__device__ __forceinline__ float bf2f(short s) {
  return __builtin_bit_cast(float, ((unsigned)(unsigned short)s) << 16);
}

// One step. NO global loads anywhere in the loop: x comes from LDS (staged
// once), so no vmcnt wait exists -> output stores retire asynchronously at
// HBM pace and never serialize with compute. One barrier per step.
// Output for step T is read back COALESCED from the just-written h buffer
// (bf16->f32, 1KB dwordx4 per wave-row).
#define CSTEP(HR, HW, T)                                                      \
  {                                                                           \
    const short* xa = lds + XA_OFF + (T) * XA_T;                              \
    short4v xl0a = *(const short4v*)(xa + colA * 36 + kq * 8);                \
    short4v xl0b = *(const short4v*)(xa + colA * 36 + kq * 8 + 4);            \
    short4v xl1a = *(const short4v*)(xa + (colA + 16) * 36 + kq * 8);         \
    short4v xl1b = *(const short4v*)(xa + (colA + 16) * 36 + kq * 8 + 4);     \
    float4v x32v0 = *(const float4v*)(x32 + (T) * BTILE + kq * 4);            \
    float4v x32v1 = *(const float4v*)(x32 + (T) * BTILE + 16 + kq * 4);       \
    float4v acc[2][2];                                                        \
    _Pragma("unroll") for (int m = 0; m < 2; ++m)                             \
      _Pragma("unroll") for (int n = 0; n < 2; ++n)                           \
        _Pragma("unroll") for (int i = 0; i < 4; ++i)                         \
          acc[m][n][i] = hst[m][n][i] + bc[n];                                \
    const short* hb = lds + (HR);                                             \
    _Pragma("unroll") for (int ks = 0; ks < 8; ++ks) {                        \
      const int k = ks * 32 + kq * 8;                                         \
      short8 a0 = *(const short8*)(hb + colA * H_STRIDE + k);                 \
      short8 a1 = *(const short8*)(hb + (16 + colA) * H_STRIDE + k);          \
      acc[0][0] = __builtin_amdgcn_mfma_f32_16x16x32_bf16(a0, wf[0][ks], acc[0][0], 0, 0, 0); \
      acc[0][1] = __builtin_amdgcn_mfma_f32_16x16x32_bf16(a0, wf[1][ks], acc[0][1], 0, 0, 0); \
      acc[1][0] = __builtin_amdgcn_mfma_f32_16x16x32_bf16(a1, wf[0][ks], acc[1][0], 0, 0, 0); \
      acc[1][1] = __builtin_amdgcn_mfma_f32_16x16x32_bf16(a1, wf[1][ks], acc[1][1], 0, 0, 0); \
    }                                                                         \
    {                                                                         \
      short8 xa0, xa1;                                                        \
      _Pragma("unroll") for (int j = 0; j < 4; ++j) {                         \
        xa0[j] = xl0a[j]; xa0[4 + j] = xl0b[j];                               \
        xa1[j] = xl1a[j]; xa1[4 + j] = xl1b[j];                               \
      }                                                                       \
      acc[0][0] = __builtin_amdgcn_mfma_f32_16x16x32_bf16(xa0, win0[0], acc[0][0], 0, 0, 0); \
      acc[0][1] = __builtin_amdgcn_mfma_f32_16x16x32_bf16(xa0, win0[1], acc[0][1], 0, 0, 0); \
      acc[1][0] = __builtin_amdgcn_mfma_f32_16x16x32_bf16(xa1, win0[0], acc[1][0], 0, 0, 0); \
      acc[1][1] = __builtin_amdgcn_mfma_f32_16x16x32_bf16(xa1, win0[1], acc[1][1], 0, 0, 0); \
    }                                                                         \
    _Pragma("unroll") for (int n = 0; n < 2; ++n)                             \
      _Pragma("unroll") for (int i = 0; i < 4; ++i) {                         \
        acc[0][n][i] += w32[n] * x32v0[i];                                    \
        acc[1][n][i] += w32[n] * x32v1[i];                                    \
      }                                                                       \
    _Pragma("unroll") for (int m = 0; m < 2; ++m)                             \
      _Pragma("unroll") for (int n = 0; n < 2; ++n)                           \
        _Pragma("unroll") for (int i = 0; i < 4; ++i) {                       \
          float hn = fmaxf(0.5f * acc[m][n][i], 0.0f);                        \
          hst[m][n][i] = hn;                                                  \
          lds[(HW) + (m * 16 + kq * 4 + i) * H_STRIDE + c0 + n * 16 + colA] = \
              f2bf(hn);                                                       \
        }                                                                     \
    __builtin_amdgcn_sched_barrier(0);                                        \
    asm volatile("s_waitcnt lgkmcnt(0)" ::: "memory");                        \
    __builtin_amdgcn_s_barrier();                                             \
    __builtin_amdgcn_sched_barrier(0);                                        \
    _Pragma("unroll") for (int j = 0; j < 4; ++j) {                           \
      short4v hv = *(const short4v*)(lds + (HW) + (4 * wave + j) * H_STRIDE + 4 * lane); \
      float4v ov;                                                             \
      ov[0] = bf2f(hv[0]); ov[1] = bf2f(hv[1]);                               \
      ov[2] = bf2f(hv[2]); ov[3] = bf2f(hv[3]);                               \
      *(float4v*)(outg + j * HID) = ov;                                       \
    }                                                                         \
    outg += outstep;                                                          \
  }

__global__ __launch_bounds__(NTH, 2)
void ctrnn_kernel(const float* __restrict__ x, const int* __restrict__ sub_id,
                  const float* __restrict__ gates, const float* __restrict__ W_in,
                  const float* __restrict__ b_in, const float* __restrict__ W_h,
                  const float* __restrict__ b_h, float* __restrict__ out)
{
  extern __shared__ short lds[];
  float* x32 = (float*)((char*)lds + X32_BYTE);
  const int tid  = threadIdx.x;
  const int lane = tid & 63;
  const int wave = tid >> 6;
  const int colA = lane & 15;   // A-row / C-col within tile
  const int kq   = lane >> 4;   // k-chunk / C-row group
  const int c0   = wave * 32;   // wave's output-column base (8 waves x 32)
  const int brow0 = blockIdx.x * BTILE;

  const int sid = sub_id[0];
  const float* grow = gates + sid * HID;

  // ---- zero h buffer 0 (h0 = 0) ----
  {
    int* ldsi = (int*)lds;
    for (int i = tid; i < HBUF / 2; i += NTH) ldsi[i] = 0;
  }

  // ---- stage ALL 50 x-tiles: bf16 matrix part + f32 k=32 plane ----
  {
    const int xstep = BATCH * INPUT;
    for (int e = tid; e < T_SEQ * BTILE * INPUT; e += NTH) {
      int t = e / (BTILE * INPUT);
      int rem = e - t * (BTILE * INPUT);
      int r = rem / INPUT, c = rem - r * INPUT;
      float v = x[(size_t)t * xstep + (size_t)(brow0 + r) * INPUT + c];
      lds[XA_OFF + t * XA_T + r * 36 + c] = f2bf(v);
      if (c == 32) x32[t * BTILE + r] = v;
    }
  }

  // ---- t-invariant operands in registers ----
  short8 wf[2][8];    // W_h' = diag(g)*W_h B-fragments (64 VGPRs)
  short8 win0[2];     // W_in k=0..31 B-fragments
  float  w32[2];      // W_in k=32 column (rank-1, f32)
  float  bc[2];       // b_in + g*b_h
  #pragma unroll
  for (int n = 0; n < 2; ++n) {
    const int col = c0 + n * 16 + colA;
    const float g = grow[col];
    #pragma unroll
    for (int ks = 0; ks < 8; ++ks) {
      const float* wp = W_h + col * HID + ks * 32 + kq * 8;
      float4v w0 = *(const float4v*)wp;
      float4v w1 = *(const float4v*)(wp + 4);
      short8 f;
      f[0] = f2bf(g * w0[0]); f[1] = f2bf(g * w0[1]);
      f[2] = f2bf(g * w0[2]); f[3] = f2bf(g * w0[3]);
      f[4] = f2bf(g * w1[0]); f[5] = f2bf(g * w1[1]);
      f[6] = f2bf(g * w1[2]); f[7] = f2bf(g * w1[3]);
      wf[n][ks] = f;
    }
    {
      const float* wip = W_in + col * INPUT + kq * 8;   // k < 32
      short8 f;
      #pragma unroll
      for (int j = 0; j < 8; ++j) f[j] = f2bf(wip[j]);
      win0[n] = f;
    }
    w32[n] = W_in[col * INPUT + 32];
    bc[n]  = b_in[col] + g * b_h[col];
  }

  // persistent f32 h master at MFMA C-layout
  float4v hst[2][2];
  #pragma unroll
  for (int m = 0; m < 2; ++m)
    #pragma unroll
    for (int n = 0; n < 2; ++n)
      #pragma unroll
      for (int i = 0; i < 4; ++i) hst[m][n][i] = 0.0f;

  // coalesced store base: wave w owns tile rows 4w..4w+3, lane covers 16B
  float* outg = out + (size_t)(brow0 + 4 * wave) * HID + 4 * lane;
  const int outstep = BATCH * HID;

  __syncthreads();   // h0 zeroed + all x staged

  #pragma unroll 1
  for (int t2 = 0; t2 < T_SEQ / 2; ++t2) {
    CSTEP(H0, H1, 2 * t2);        // even: read buf0, write buf1
    CSTEP(H1, H0, 2 * t2 + 1);    // odd:  read buf1, write buf0
  }

  // h_last == output[T-1], held in H0 (written by step T-1)
  {
    float* hl = out + (size_t)T_SEQ * BATCH * HID +
                (size_t)(brow0 + 4 * wave) * HID + 4 * lane;
    #pragma unroll
    for (int j = 0; j < 4; ++j) {
      short4v hv = *(const short4v*)(lds + H0 + (4 * wave + j) * H_STRIDE + 4 * lane);
      float4v ov;
      ov[0] = bf2f(hv[0]); ov[1] = bf2f(hv[1]);
      ov[2] = bf2f(hv[2]); ov[3] = bf2f(hv[3]);
      *(float4v*)(hl + j * HID) = ov;
    }
  }
}

extern "C" void kernel_launch(void* const* d_in, const int* in_sizes, int n_in,
                              void* d_out, int out_size, void* d_ws, size_t ws_size,
                              hipStream_t stream) {
  const float* x    = (const float*)d_in[0];
  const int*   sid  = (const int*)  d_in[1];
  const float* gts  = (const float*)d_in[2];
  const float* W_in = (const float*)d_in[3];
  const float* b_in = (const float*)d_in[4];
  const float* W_h  = (const float*)d_in[5];
  const float* b_h  = (const float*)d_in[6];
  float* out = (float*)d_out;

  (void)hipFuncSetAttribute(reinterpret_cast<const void*>(ctrnn_kernel),
                            hipFuncAttributeMaxDynamicSharedMemorySize,
                            (int)LDS_BYTES);
  ctrnn_kernel<<<BATCH / BTILE, NTH, LDS_BYTES, stream>>>(x, sid, gts, W_in,
                                                          b_in, W_h, b_h, out);
}